// Round 1
// baseline (315.989 us; speedup 1.0000x reference)
//
#include <hip/hip_runtime.h>
#include <math.h>

#define BB 512
#define LL 128
#define DD 256
#define NREST 127            // L-1
#define ROW_STRIDE (LL*DD)   // 32768 floats per batch element
#define EPSN 1e-12f

#define TI 128   // i-tile per block
#define DC 32    // d chunk
#define LDA 33   // padded LDS leading dim

// ---------------- Kernel 1: per-row inverse L2 norms ----------------
__global__ __launch_bounds__(256) void norm_kernel(const float* __restrict__ in,
                                                   float* __restrict__ invn) {
    int wid  = threadIdx.x >> 6;
    int lane = threadIdx.x & 63;
    int row  = blockIdx.x * 4 + wid;            // 0..65535
    const float4* src = (const float4*)(in + (size_t)row * DD);
    float4 v = src[lane];
    float ss = v.x*v.x + v.y*v.y + v.z*v.z + v.w*v.w;
    #pragma unroll
    for (int off = 32; off; off >>= 1) ss += __shfl_xor(ss, off);
    if (lane == 0) invn[row] = 1.0f / fmaxf(sqrtf(ss), EPSN);
}

// ---------------- Kernel 2: scores + exp + k-sum -> E^T[j][i] ----------------
__global__ __launch_bounds__(256) void score_kernel(const float* __restrict__ in,
                                                    const float* __restrict__ invn,
                                                    float* __restrict__ ET) {
    __shared__ float sA[TI * LDA];   // anchors tile [i][d]
    __shared__ float sR[128 * LDA];  // rest tile   [k][d] (row 127 zeroed)

    const int tid = threadIdx.x;
    const int i0  = blockIdx.x * TI;
    const int j   = blockIdx.y;

    float acc[8][8];
    #pragma unroll
    for (int a = 0; a < 8; ++a)
        #pragma unroll
        for (int b = 0; b < 8; ++b) acc[a][b] = 0.0f;

    const int ti = tid & 15;   // i sub-index (i = ti + 16*ii)
    const int tk = tid >> 4;   // k group     (k = tk*8 + kk)

    for (int d0 = 0; d0 < DD; d0 += DC) {
        // stage A: 128 rows x 32 cols, pre-scaled by inv norm (anchors: l=0)
        #pragma unroll
        for (int it = 0; it < 4; ++it) {
            int idx = it * 1024 + tid * 4;
            int row = idx >> 5;
            int col = idx & 31;
            float sc = invn[(i0 + row) * LL];
            const float4 v = *(const float4*)(in + (size_t)(i0 + row) * ROW_STRIDE + d0 + col);
            float* dst = &sA[row * LDA + col];
            dst[0] = v.x * sc; dst[1] = v.y * sc; dst[2] = v.z * sc; dst[3] = v.w * sc;
        }
        // stage R: rows k=0..126 (rest: l=k+1), row 127 zero
        #pragma unroll
        for (int it = 0; it < 4; ++it) {
            int idx = it * 1024 + tid * 4;
            int row = idx >> 5;
            int col = idx & 31;
            float* dst = &sR[row * LDA + col];
            if (row < NREST) {
                float sc = invn[j * LL + row + 1];
                const float4 v = *(const float4*)(in + (size_t)j * ROW_STRIDE + (size_t)(row + 1) * DD + d0 + col);
                dst[0] = v.x * sc; dst[1] = v.y * sc; dst[2] = v.z * sc; dst[3] = v.w * sc;
            } else {
                dst[0] = 0.f; dst[1] = 0.f; dst[2] = 0.f; dst[3] = 0.f;
            }
        }
        __syncthreads();

        #pragma unroll 4
        for (int d = 0; d < DC; ++d) {
            float a[8], r[8];
            #pragma unroll
            for (int ii = 0; ii < 8; ++ii) a[ii] = sA[(ti + 16 * ii) * LDA + d];
            #pragma unroll
            for (int kk = 0; kk < 8; ++kk) r[kk] = sR[(tk * 8 + kk) * LDA + d];
            #pragma unroll
            for (int ii = 0; ii < 8; ++ii)
                #pragma unroll
                for (int kk = 0; kk < 8; ++kk)
                    acc[ii][kk] = fmaf(a[ii], r[kk], acc[ii][kk]);
        }
        __syncthreads();
    }

    // exp + partial k-sum (T = 1.0 so no divide)
    float esum[8];
    #pragma unroll
    for (int ii = 0; ii < 8; ++ii) {
        float s = 0.f;
        #pragma unroll
        for (int kk = 0; kk < 8; ++kk) {
            int k = tk * 8 + kk;
            if (k < NREST) s += __expf(acc[ii][kk]);
        }
        esum[ii] = s;
    }

    // cross-tk reduction through LDS (reuse sA: 128 x 16 floats)
    __syncthreads();
    float* red = sA;
    #pragma unroll
    for (int ii = 0; ii < 8; ++ii) red[(ti + 16 * ii) * 16 + tk] = esum[ii];
    __syncthreads();
    if (tid < TI) {
        float s = 0.f;
        #pragma unroll
        for (int t = 0; t < 16; ++t) s += red[tid * 16 + t];
        ET[(size_t)j * BB + i0 + tid] = s;   // coalesced over i
    }
}

// ---------------- Kernel 3: per-i tot/pos and log term ----------------
__global__ __launch_bounds__(256) void rowreduce_kernel(const float* __restrict__ ET,
                                                        const int* __restrict__ label,
                                                        float* __restrict__ terms) {
    int i  = blockIdx.x;
    int li = label[i];
    float tot = 0.f, pos = 0.f;
    for (int j = threadIdx.x; j < BB; j += 256) {
        float e = ET[(size_t)j * BB + i];
        tot += e;
        if (label[j] == li) pos += e;
    }
    #pragma unroll
    for (int off = 32; off; off >>= 1) {
        tot += __shfl_xor(tot, off);
        pos += __shfl_xor(pos, off);
    }
    __shared__ float st[4], sp[4];
    int wid = threadIdx.x >> 6;
    if ((threadIdx.x & 63) == 0) { st[wid] = tot; sp[wid] = pos; }
    __syncthreads();
    if (threadIdx.x == 0) {
        float t = st[0] + st[1] + st[2] + st[3];
        float p = sp[0] + sp[1] + sp[2] + sp[3];
        terms[i] = logf(t) - logf(p);
    }
}

// ---------------- Kernel 4: mean over i -> loss ----------------
__global__ __launch_bounds__(256) void final_kernel(const float* __restrict__ terms,
                                                    float* __restrict__ out) {
    float s = terms[threadIdx.x] + terms[threadIdx.x + 256];
    #pragma unroll
    for (int off = 32; off; off >>= 1) s += __shfl_xor(s, off);
    __shared__ float sw[4];
    int wid = threadIdx.x >> 6;
    if ((threadIdx.x & 63) == 0) sw[wid] = s;
    __syncthreads();
    if (threadIdx.x == 0) out[0] = (sw[0] + sw[1] + sw[2] + sw[3]) * (1.0f / BB);
}

extern "C" void kernel_launch(void* const* d_in, const int* in_sizes, int n_in,
                              void* d_out, int out_size, void* d_ws, size_t ws_size,
                              hipStream_t stream) {
    const float* in    = (const float*)d_in[0];
    const int*   label = (const int*)d_in[1];
    float*       out   = (float*)d_out;

    float* invn  = (float*)d_ws;                 // 65536 floats
    float* ET    = invn + (size_t)BB * LL;       // 512*512 floats, E^T[j][i]
    float* terms = ET + (size_t)BB * BB;         // 512 floats

    norm_kernel<<<(BB * LL) / 4, 256, 0, stream>>>(in, invn);
    score_kernel<<<dim3(BB / TI, BB), 256, 0, stream>>>(in, invn, ET);
    rowreduce_kernel<<<BB, 256, 0, stream>>>(ET, label, terms);
    final_kernel<<<1, 256, 0, stream>>>(terms, out);
}

// Round 2
// 165.100 us; speedup vs baseline: 1.9139x; 1.9139x over previous
//
#include <hip/hip_runtime.h>
#include <math.h>

#define BB 512
#define LL 128
#define DD 256
#define NREST 127            // L-1
#define EPSN 1e-12f

#define TI 128               // i-tile and k-tile per block
#define BK 64                // K chunk (d dimension)
#define P  72                // padded LDS stride in halfs (64 + 8)

typedef _Float16 half8  __attribute__((ext_vector_type(8)));
typedef _Float16 half4v __attribute__((ext_vector_type(4)));
typedef float    f32x4  __attribute__((ext_vector_type(4)));

// ---------------- Kernel 1: per-row inverse L2 norms ----------------
__global__ __launch_bounds__(256) void norm_kernel(const float* __restrict__ in,
                                                   float* __restrict__ invn) {
    int wid  = threadIdx.x >> 6;
    int lane = threadIdx.x & 63;
    int row  = blockIdx.x * 4 + wid;            // 0..65535
    const float4* src = (const float4*)(in + (size_t)row * DD);
    float4 v = src[lane];
    float ss = v.x*v.x + v.y*v.y + v.z*v.z + v.w*v.w;
    #pragma unroll
    for (int off = 32; off; off >>= 1) ss += __shfl_xor(ss, off);
    if (lane == 0) invn[row] = 1.0f / fmaxf(sqrtf(ss), EPSN);
}

// ------- Kernel 2: MFMA scores + exp + k-sum -> E^T[j][i] -------
// Block: i-tile of 128 anchors x all 127 rest rows of batch j, K = 256.
// 4 waves in 2x2; each wave computes 64x64 via 4x4 tiles of 16x16x32 f16 MFMA.
__global__ __launch_bounds__(256) void score_mfma_kernel(const float* __restrict__ in,
                                                         const float* __restrict__ invn,
                                                         float* __restrict__ ET) {
    __shared__ _Float16 sA[TI * P];   // anchors tile [i][d]  (f16, normalized)
    __shared__ _Float16 sR[TI * P];   // rest tile   [k][d]  (row 127 zeroed)
    __shared__ float    sP[TI * 2];   // per-i partial sums from the 2 wave_n halves

    const int tid  = threadIdx.x;
    const int i0   = blockIdx.x * TI;
    const int j    = blockIdx.y;

    const int lane = tid & 63;
    const int w    = tid >> 6;
    const int wm   = w & 1;           // wave row  (i)
    const int wn   = w >> 1;          // wave col  (k_rest)
    const int rowf = lane & 15;
    const int quad = lane >> 4;

    f32x4 acc[4][4];
    #pragma unroll
    for (int a = 0; a < 4; ++a)
        #pragma unroll
        for (int b = 0; b < 4; ++b) acc[a][b] = (f32x4){0.f, 0.f, 0.f, 0.f};

    for (int d0 = 0; d0 < DD; d0 += BK) {
        // ---- stage A and R chunks (f32 load, normalize, cvt f16) ----
        #pragma unroll
        for (int it = 0; it < 8; ++it) {
            int idx = it * 256 + tid;        // 0..2047
            int row = idx >> 4;              // 0..127
            int c4  = idx & 15;              // 0..15 (x4 floats)
            // A: anchor rows (batch i0+row, l=0)
            {
                int grow = i0 + row;
                float sc = invn[grow * LL];
                const float4 v = *(const float4*)(in + (size_t)grow * LL * DD + d0 + c4 * 4);
                half4v h = { (_Float16)(v.x * sc), (_Float16)(v.y * sc),
                             (_Float16)(v.z * sc), (_Float16)(v.w * sc) };
                *(half4v*)(&sA[row * P + c4 * 4]) = h;
            }
            // R: rest rows (batch j, l=row+1); row 127 zeroed
            {
                half4v h = { (_Float16)0.f, (_Float16)0.f, (_Float16)0.f, (_Float16)0.f };
                if (row < NREST) {
                    int l = row + 1;
                    float sc = invn[j * LL + l];
                    const float4 v = *(const float4*)(in + ((size_t)j * LL + l) * DD + d0 + c4 * 4);
                    h = (half4v){ (_Float16)(v.x * sc), (_Float16)(v.y * sc),
                                  (_Float16)(v.z * sc), (_Float16)(v.w * sc) };
                }
                *(half4v*)(&sR[row * P + c4 * 4]) = h;
            }
        }
        __syncthreads();

        // ---- MFMA over this 64-deep K chunk: 2 k-steps of 32 ----
        #pragma unroll
        for (int ks = 0; ks < 2; ++ks) {
            const int off = ks * 32 + quad * 8;
            half8 af[4], bf[4];
            #pragma unroll
            for (int mt = 0; mt < 4; ++mt)
                af[mt] = *(const half8*)(&sA[(wm * 64 + mt * 16 + rowf) * P + off]);
            #pragma unroll
            for (int nt = 0; nt < 4; ++nt)
                bf[nt] = *(const half8*)(&sR[(wn * 64 + nt * 16 + rowf) * P + off]);
            #pragma unroll
            for (int mt = 0; mt < 4; ++mt)
                #pragma unroll
                for (int nt = 0; nt < 4; ++nt)
                    acc[mt][nt] = __builtin_amdgcn_mfma_f32_16x16x32_f16(af[mt], bf[nt], acc[mt][nt], 0, 0, 0);
        }
        __syncthreads();
    }

    // ---- epilogue: exp + sum over this wave's 64 k values ----
    // C/D layout: col(n) = lane&15, row(m) = quad*4 + reg
    #pragma unroll
    for (int mt = 0; mt < 4; ++mt) {
        float s[4];
        #pragma unroll
        for (int r = 0; r < 4; ++r) s[r] = 0.f;
        #pragma unroll
        for (int nt = 0; nt < 4; ++nt) {
            int n = wn * 64 + nt * 16 + rowf;   // global k_rest index
            bool valid = (n < NREST);
            #pragma unroll
            for (int r = 0; r < 4; ++r)
                if (valid) s[r] += __expf(acc[mt][nt][r]);
        }
        #pragma unroll
        for (int r = 0; r < 4; ++r) {
            #pragma unroll
            for (int off = 1; off < 16; off <<= 1) s[r] += __shfl_xor(s[r], off);
        }
        if (rowf == 0) {
            #pragma unroll
            for (int r = 0; r < 4; ++r)
                sP[(wm * 64 + mt * 16 + quad * 4 + r) * 2 + wn] = s[r];
        }
    }
    __syncthreads();
    if (tid < TI) {
        float e = sP[tid * 2] + sP[tid * 2 + 1];
        ET[(size_t)j * BB + i0 + tid] = e;      // coalesced over i
    }
}

// ---------------- Kernel 3: per-i tot/pos and log term ----------------
__global__ __launch_bounds__(256) void rowreduce_kernel(const float* __restrict__ ET,
                                                        const int* __restrict__ label,
                                                        float* __restrict__ terms) {
    int i  = blockIdx.x;
    int li = label[i];
    float tot = 0.f, pos = 0.f;
    for (int jj = threadIdx.x; jj < BB; jj += 256) {
        float e = ET[(size_t)jj * BB + i];
        tot += e;
        if (label[jj] == li) pos += e;
    }
    #pragma unroll
    for (int off = 32; off; off >>= 1) {
        tot += __shfl_xor(tot, off);
        pos += __shfl_xor(pos, off);
    }
    __shared__ float st[4], sp[4];
    int wid = threadIdx.x >> 6;
    if ((threadIdx.x & 63) == 0) { st[wid] = tot; sp[wid] = pos; }
    __syncthreads();
    if (threadIdx.x == 0) {
        float t = st[0] + st[1] + st[2] + st[3];
        float p = sp[0] + sp[1] + sp[2] + sp[3];
        terms[i] = logf(t) - logf(p);
    }
}

// ---------------- Kernel 4: mean over i -> loss ----------------
__global__ __launch_bounds__(256) void final_kernel(const float* __restrict__ terms,
                                                    float* __restrict__ out) {
    float s = terms[threadIdx.x] + terms[threadIdx.x + 256];
    #pragma unroll
    for (int off = 32; off; off >>= 1) s += __shfl_xor(s, off);
    __shared__ float sw[4];
    int wid = threadIdx.x >> 6;
    if ((threadIdx.x & 63) == 0) sw[wid] = s;
    __syncthreads();
    if (threadIdx.x == 0) out[0] = (sw[0] + sw[1] + sw[2] + sw[3]) * (1.0f / BB);
}

extern "C" void kernel_launch(void* const* d_in, const int* in_sizes, int n_in,
                              void* d_out, int out_size, void* d_ws, size_t ws_size,
                              hipStream_t stream) {
    const float* in    = (const float*)d_in[0];
    const int*   label = (const int*)d_in[1];
    float*       out   = (float*)d_out;

    float* invn  = (float*)d_ws;                 // 65536 floats
    float* ET    = invn + (size_t)BB * LL;       // 512*512 floats, E^T[j][i]
    float* terms = ET + (size_t)BB * BB;         // 512 floats

    norm_kernel<<<(BB * LL) / 4, 256, 0, stream>>>(in, invn);
    score_mfma_kernel<<<dim3(BB / TI, BB), 256, 0, stream>>>(in, invn, ET);
    rowreduce_kernel<<<BB, 256, 0, stream>>>(ET, label, terms);
    final_kernel<<<1, 256, 0, stream>>>(terms, out);
}

// Round 3
// 134.086 us; speedup vs baseline: 2.3566x; 1.2313x over previous
//
#include <hip/hip_runtime.h>
#include <math.h>

#define BB 512
#define LL 128
#define DD 256
#define NREST 127            // L-1
#define EPSN 1e-12f

#define TI 128               // i-tile and k-tile per block
#define BK 64                // K chunk (d dimension)

typedef _Float16 half8  __attribute__((ext_vector_type(8)));
typedef _Float16 half4v __attribute__((ext_vector_type(4)));
typedef float    f32x4  __attribute__((ext_vector_type(4)));

// async global->LDS, 16B per lane; lptr must be wave-uniform (HW adds lane*16)
#define GLD16(gp, lp) __builtin_amdgcn_global_load_lds( \
    (const __attribute__((address_space(1))) void*)(gp), \
    (__attribute__((address_space(3))) void*)(lp), 16, 0, 0)

// ---- Kernel 1: norm + normalize + cvt f16, split into Af (anchors) / Rf (rest) ----
// Rf[b][r][d] holds row l=r+1; Rf[b][127][*] is zeroed so score needs no masking in staging.
__global__ __launch_bounds__(256) void prep_kernel(const float* __restrict__ in,
                                                   _Float16* __restrict__ Af,
                                                   _Float16* __restrict__ Rf) {
    int wid  = threadIdx.x >> 6;
    int lane = threadIdx.x & 63;
    int row  = blockIdx.x * 4 + wid;            // 0..65535
    int b    = row >> 7;
    int l    = row & 127;
    const float4 v = ((const float4*)(in + (size_t)row * DD))[lane];
    float ss = v.x*v.x + v.y*v.y + v.z*v.z + v.w*v.w;
    #pragma unroll
    for (int off = 32; off; off >>= 1) ss += __shfl_xor(ss, off);
    float sc = 1.0f / fmaxf(sqrtf(ss), EPSN);
    half4v h = { (_Float16)(v.x * sc), (_Float16)(v.y * sc),
                 (_Float16)(v.z * sc), (_Float16)(v.w * sc) };
    if (l == 0) {
        *(half4v*)(Af + (size_t)b * DD + lane * 4) = h;
        // zero the padding row 127 of this batch's rest block
        *(half4v*)(Rf + ((size_t)b * LL + 127) * DD + lane * 4) =
            (half4v){ (_Float16)0.f, (_Float16)0.f, (_Float16)0.f, (_Float16)0.f };
    } else {
        *(half4v*)(Rf + ((size_t)b * LL + (l - 1)) * DD + lane * 4) = h;
    }
}

// ------- Kernel 2: MFMA scores + exp + k-sum -> E^T[j][i] -------
// Block: 128 anchors x 128 rest rows (127 valid) of batch j, K = 256.
// 4 waves in 2x2; each wave 64x64 via 4x4 tiles of 16x16x32 f16 MFMA.
// Staging: global_load_lds dwordx4, unpadded LDS [row][64] per chunk (m97 layout).
__global__ __launch_bounds__(256) void score_kernel(const _Float16* __restrict__ Af,
                                                    const _Float16* __restrict__ Rf,
                                                    float* __restrict__ ET) {
    __shared__ _Float16 sA[TI * BK];   // 16 KB
    __shared__ _Float16 sR[TI * BK];   // 16 KB
    __shared__ float    sP[TI * 2];

    const int tid  = threadIdx.x;
    const int i0   = blockIdx.x * TI;
    const int j    = blockIdx.y;

    const int lane = tid & 63;
    const int w    = tid >> 6;
    const int wm   = w & 1;            // wave row (i)
    const int wn   = w >> 1;           // wave col (k_rest)
    const int rowf = lane & 15;
    const int quad = lane >> 4;
    const int lrow = lane >> 3;        // staging: row within 8-row group
    const int g    = lane & 7;         // staging: 16B granule within row

    f32x4 acc[4][4];
    #pragma unroll
    for (int a = 0; a < 4; ++a)
        #pragma unroll
        for (int b = 0; b < 4; ++b) acc[a][b] = (f32x4){0.f, 0.f, 0.f, 0.f};

    const _Float16* aBase = Af + (size_t)i0 * DD;
    const _Float16* rBase = Rf + (size_t)j * LL * DD;

    for (int d0 = 0; d0 < DD; d0 += BK) {
        // ---- async stage: each wave issues 4 x 1KB per tile ----
        #pragma unroll
        for (int t = 0; t < 4; ++t) {
            int grp = w * 4 + t;               // 0..15, 8 rows each
            int r   = grp * 8 + lrow;          // 0..127
            GLD16(aBase + (size_t)r * DD + d0 + g * 8, &sA[grp * 512]);
            GLD16(rBase + (size_t)r * DD + d0 + g * 8, &sR[grp * 512]);
        }
        __syncthreads();

        // ---- MFMA over this 64-deep K chunk: 2 k-steps of 32 ----
        #pragma unroll
        for (int ks = 0; ks < 2; ++ks) {
            const int off = ks * 32 + quad * 8;
            half8 af[4], bf[4];
            #pragma unroll
            for (int mt = 0; mt < 4; ++mt)
                af[mt] = *(const half8*)(&sA[(wm * 64 + mt * 16 + rowf) * BK + off]);
            #pragma unroll
            for (int nt = 0; nt < 4; ++nt)
                bf[nt] = *(const half8*)(&sR[(wn * 64 + nt * 16 + rowf) * BK + off]);
            #pragma unroll
            for (int mt = 0; mt < 4; ++mt)
                #pragma unroll
                for (int nt = 0; nt < 4; ++nt)
                    acc[mt][nt] = __builtin_amdgcn_mfma_f32_16x16x32_f16(af[mt], bf[nt], acc[mt][nt], 0, 0, 0);
        }
        __syncthreads();
    }

    // ---- epilogue: exp + sum over this wave's 64 k values ----
    // C/D layout: col(n) = lane&15, row(m) = quad*4 + reg  (verified R2)
    #pragma unroll
    for (int mt = 0; mt < 4; ++mt) {
        float s[4];
        #pragma unroll
        for (int r = 0; r < 4; ++r) s[r] = 0.f;
        #pragma unroll
        for (int nt = 0; nt < 4; ++nt) {
            int n = wn * 64 + nt * 16 + rowf;   // global k_rest index
            bool valid = (n < NREST);
            #pragma unroll
            for (int r = 0; r < 4; ++r)
                if (valid) s[r] += __expf(acc[mt][nt][r]);
        }
        #pragma unroll
        for (int r = 0; r < 4; ++r) {
            #pragma unroll
            for (int off = 1; off < 16; off <<= 1) s[r] += __shfl_xor(s[r], off);
        }
        if (rowf == 0) {
            #pragma unroll
            for (int r = 0; r < 4; ++r)
                sP[(wm * 64 + mt * 16 + quad * 4 + r) * 2 + wn] = s[r];
        }
    }
    __syncthreads();
    if (tid < TI) {
        float e = sP[tid * 2] + sP[tid * 2 + 1];
        ET[(size_t)j * BB + i0 + tid] = e;      // coalesced over i
    }
}

// ---------------- Kernel 3: per-i tot/pos and log term ----------------
__global__ __launch_bounds__(256) void rowreduce_kernel(const float* __restrict__ ET,
                                                        const int* __restrict__ label,
                                                        float* __restrict__ terms) {
    int i  = blockIdx.x;
    int li = label[i];
    float tot = 0.f, pos = 0.f;
    for (int jj = threadIdx.x; jj < BB; jj += 256) {
        float e = ET[(size_t)jj * BB + i];
        tot += e;
        if (label[jj] == li) pos += e;
    }
    #pragma unroll
    for (int off = 32; off; off >>= 1) {
        tot += __shfl_xor(tot, off);
        pos += __shfl_xor(pos, off);
    }
    __shared__ float st[4], sp[4];
    int wid = threadIdx.x >> 6;
    if ((threadIdx.x & 63) == 0) { st[wid] = tot; sp[wid] = pos; }
    __syncthreads();
    if (threadIdx.x == 0) {
        float t = st[0] + st[1] + st[2] + st[3];
        float p = sp[0] + sp[1] + sp[2] + sp[3];
        terms[i] = logf(t) - logf(p);
    }
}

// ---------------- Kernel 4: mean over i -> loss ----------------
__global__ __launch_bounds__(256) void final_kernel(const float* __restrict__ terms,
                                                    float* __restrict__ out) {
    float s = terms[threadIdx.x] + terms[threadIdx.x + 256];
    #pragma unroll
    for (int off = 32; off; off >>= 1) s += __shfl_xor(s, off);
    __shared__ float sw[4];
    int wid = threadIdx.x >> 6;
    if ((threadIdx.x & 63) == 0) sw[wid] = s;
    __syncthreads();
    if (threadIdx.x == 0) out[0] = (sw[0] + sw[1] + sw[2] + sw[3]) * (1.0f / BB);
}

extern "C" void kernel_launch(void* const* d_in, const int* in_sizes, int n_in,
                              void* d_out, int out_size, void* d_ws, size_t ws_size,
                              hipStream_t stream) {
    const float* in    = (const float*)d_in[0];
    const int*   label = (const int*)d_in[1];
    float*       out   = (float*)d_out;

    _Float16* Af = (_Float16*)d_ws;                       // 512*256 halfs (256 KB)
    _Float16* Rf = Af + (size_t)BB * DD;                  // 512*128*256 halfs (32 MB)
    float*    ET = (float*)(Rf + (size_t)BB * LL * DD);   // 512*512 f32 (1 MB), E^T[j][i]
    float* terms = ET + (size_t)BB * BB;                  // 512 f32

    prep_kernel<<<(BB * LL) / 4, 256, 0, stream>>>(in, Af, Rf);
    score_kernel<<<dim3(BB / TI, BB), 256, 0, stream>>>(Af, Rf, ET);
    rowreduce_kernel<<<BB, 256, 0, stream>>>(ET, label, terms);
    final_kernel<<<1, 256, 0, stream>>>(terms, out);
}

// Round 4
// 128.874 us; speedup vs baseline: 2.4519x; 1.0404x over previous
//
#include <hip/hip_runtime.h>
#include <math.h>

#define BB 512
#define LL 128
#define DD 256
#define NREST 127            // L-1
#define EPSN 1e-12f

#define TI 128               // i-tile and k-tile per block

typedef float f32x4 __attribute__((ext_vector_type(4)));
typedef long  long2v __attribute__((ext_vector_type(2)));

// async global->LDS, 16B per lane; LDS base wave-uniform (HW adds lane*16)
#define GLD16(gp, lp) __builtin_amdgcn_global_load_lds( \
    (const __attribute__((address_space(1))) void*)(gp), \
    (__attribute__((address_space(3))) void*)(lp), 16, 0, 0)

// ---- Kernel 1: norm + normalize + cvt fp8(e4m3), column-permuted, split Af/Rf ----
// Row layout (256 B): within each 64-byte block, 8-byte groups are stored in order
// 0,4,1,5,2,6,3,7 (orig group g -> pos g<4 ? 2g : 2(g-4)+1). Then a 16-byte LDS
// fragment read at offset quad*16 yields [ks0 frag | ks1 frag] for that quad.
// Rf[b][r] holds row l=r+1; Rf[b][127] zeroed so score needs no masking while staging.
__global__ __launch_bounds__(256) void prep_kernel(const float* __restrict__ in,
                                                   unsigned char* __restrict__ Af,
                                                   unsigned char* __restrict__ Rf) {
    int wid  = threadIdx.x >> 6;
    int lane = threadIdx.x & 63;
    int row  = blockIdx.x * 4 + wid;            // 0..65535
    int b    = row >> 7;
    int l    = row & 127;
    const float4 v = ((const float4*)(in + (size_t)row * DD))[lane];
    float ss = v.x*v.x + v.y*v.y + v.z*v.z + v.w*v.w;
    #pragma unroll
    for (int off = 32; off; off >>= 1) ss += __shfl_xor(ss, off);
    float sc = 1.0f / fmaxf(sqrtf(ss), EPSN);

    int p = __builtin_amdgcn_cvt_pk_fp8_f32(v.x * sc, v.y * sc, 0, false);
    p     = __builtin_amdgcn_cvt_pk_fp8_f32(v.z * sc, v.w * sc, p, true);

    // permuted byte offset for this lane's 4 elements (orig elems 4*lane..4*lane+3)
    int g_all = lane >> 1;                 // 8-elem group 0..31
    int blk   = g_all >> 3;                // 64-elem block 0..3
    int g     = g_all & 7;
    int ng    = (g < 4) ? (2 * g) : (2 * (g - 4) + 1);
    int off   = blk * 64 + ng * 8 + (lane & 1) * 4;

    if (l == 0) {
        *(unsigned int*)(Af + (size_t)b * DD + off) = (unsigned int)p;
        *(unsigned int*)(Rf + ((size_t)b * LL + 127) * DD + off) = 0u;  // pad row
    } else {
        *(unsigned int*)(Rf + ((size_t)b * LL + (l - 1)) * DD + off) = (unsigned int)p;
    }
}

// ------- Kernel 2: fp8 MFMA scores + exp + k-sum -> E^T[j][i] -------
// Block: 128 anchors x 128 rest rows (127 valid) of batch j, K = 256.
// 4 waves in 2x2; each wave 64x64 via 4x4 tiles of 16x16x32 fp8_fp8 MFMA.
// LDS per chunk: A/R panels 128 rows x 64 B (one permuted 64-col block).
__global__ __launch_bounds__(256) void score_kernel(const unsigned char* __restrict__ Af,
                                                    const unsigned char* __restrict__ Rf,
                                                    float* __restrict__ ET) {
    __shared__ unsigned char sA[TI * 64];   // 8 KB
    __shared__ unsigned char sR[TI * 64];   // 8 KB
    __shared__ float         sP[TI * 2];

    const int tid  = threadIdx.x;
    const int i0   = blockIdx.x * TI;
    const int j    = blockIdx.y;

    const int lane = tid & 63;
    const int w    = tid >> 6;
    const int wm   = w & 1;            // wave row (i)
    const int wn   = w >> 1;           // wave col (k_rest)
    const int rowf = lane & 15;
    const int quad = lane >> 4;
    const int lrow = lane >> 2;        // staging: row within 16-row group
    const int gct  = lane & 3;         // staging: 16B granule within 64B row

    f32x4 acc[4][4];
    #pragma unroll
    for (int a = 0; a < 4; ++a)
        #pragma unroll
        for (int b = 0; b < 4; ++b) acc[a][b] = (f32x4){0.f, 0.f, 0.f, 0.f};

    const unsigned char* aBase = Af + (size_t)i0 * DD;
    const unsigned char* rBase = Rf + (size_t)j * LL * DD;

    for (int d0 = 0; d0 < DD; d0 += 64) {
        // ---- async stage: 8 KB per panel; 2 x 1KB instrs per wave per panel ----
        #pragma unroll
        for (int t = 0; t < 2; ++t) {
            int grp = w * 2 + t;               // 0..7, 16 rows each
            int r   = grp * 16 + lrow;
            GLD16(aBase + (size_t)r * DD + d0 + gct * 16, &sA[grp * 1024]);
            GLD16(rBase + (size_t)r * DD + d0 + gct * 16, &sR[grp * 1024]);
        }
        __syncthreads();

        // ---- fragment reads: one b128 per tile row -> both ks fragments ----
        long a0[4], a1[4], b0[4], b1[4];
        #pragma unroll
        for (int mt = 0; mt < 4; ++mt) {
            long2v lv = *(const long2v*)(&sA[(wm * 64 + mt * 16 + rowf) * 64 + quad * 16]);
            a0[mt] = lv.x; a1[mt] = lv.y;
        }
        #pragma unroll
        for (int nt = 0; nt < 4; ++nt) {
            long2v lv = *(const long2v*)(&sR[(wn * 64 + nt * 16 + rowf) * 64 + quad * 16]);
            b0[nt] = lv.x; b1[nt] = lv.y;
        }
        #pragma unroll
        for (int mt = 0; mt < 4; ++mt)
            #pragma unroll
            for (int nt = 0; nt < 4; ++nt)
                acc[mt][nt] = __builtin_amdgcn_mfma_f32_16x16x32_fp8_fp8(a0[mt], b0[nt], acc[mt][nt], 0, 0, 0);
        #pragma unroll
        for (int mt = 0; mt < 4; ++mt)
            #pragma unroll
            for (int nt = 0; nt < 4; ++nt)
                acc[mt][nt] = __builtin_amdgcn_mfma_f32_16x16x32_fp8_fp8(a1[mt], b1[nt], acc[mt][nt], 0, 0, 0);
        __syncthreads();
    }

    // ---- epilogue: exp + sum over this wave's 64 k values ----
    // C/D layout: col(n) = lane&15, row(m) = quad*4 + reg (shape-determined, dtype-indep)
    #pragma unroll
    for (int mt = 0; mt < 4; ++mt) {
        float s[4];
        #pragma unroll
        for (int r = 0; r < 4; ++r) s[r] = 0.f;
        #pragma unroll
        for (int nt = 0; nt < 4; ++nt) {
            int n = wn * 64 + nt * 16 + rowf;   // global k_rest index
            bool valid = (n < NREST);
            #pragma unroll
            for (int r = 0; r < 4; ++r)
                if (valid) s[r] += __expf(acc[mt][nt][r]);
        }
        #pragma unroll
        for (int r = 0; r < 4; ++r) {
            #pragma unroll
            for (int off = 1; off < 16; off <<= 1) s[r] += __shfl_xor(s[r], off);
        }
        if (rowf == 0) {
            #pragma unroll
            for (int r = 0; r < 4; ++r)
                sP[(wm * 64 + mt * 16 + quad * 4 + r) * 2 + wn] = s[r];
        }
    }
    __syncthreads();
    if (tid < TI) {
        float e = sP[tid * 2] + sP[tid * 2 + 1];
        ET[(size_t)j * BB + i0 + tid] = e;      // coalesced over i
    }
}

// ---- Kernel 3: per-i tot/pos, log term, atomic mean into out ----
__global__ __launch_bounds__(256) void rowreduce_kernel(const float* __restrict__ ET,
                                                        const int* __restrict__ label,
                                                        float* __restrict__ out) {
    int i  = blockIdx.x;
    int li = label[i];
    float tot = 0.f, pos = 0.f;
    for (int jj = threadIdx.x; jj < BB; jj += 256) {
        float e = ET[(size_t)jj * BB + i];
        tot += e;
        if (label[jj] == li) pos += e;
    }
    #pragma unroll
    for (int off = 32; off; off >>= 1) {
        tot += __shfl_xor(tot, off);
        pos += __shfl_xor(pos, off);
    }
    __shared__ float st[4], sp[4];
    int wid = threadIdx.x >> 6;
    if ((threadIdx.x & 63) == 0) { st[wid] = tot; sp[wid] = pos; }
    __syncthreads();
    if (threadIdx.x == 0) {
        float t = st[0] + st[1] + st[2] + st[3];
        float p = sp[0] + sp[1] + sp[2] + sp[3];
        atomicAdd(out, (logf(t) - logf(p)) * (1.0f / BB));
    }
}

extern "C" void kernel_launch(void* const* d_in, const int* in_sizes, int n_in,
                              void* d_out, int out_size, void* d_ws, size_t ws_size,
                              hipStream_t stream) {
    const float* in    = (const float*)d_in[0];
    const int*   label = (const int*)d_in[1];
    float*       out   = (float*)d_out;

    unsigned char* Af = (unsigned char*)d_ws;             // 512*256 B (128 KB)
    unsigned char* Rf = Af + (size_t)BB * DD;             // 512*128*256 B (16 MB)
    float*         ET = (float*)(Rf + (size_t)BB * LL * DD); // 512*512 f32 (1 MB)

    hipMemsetAsync(out, 0, sizeof(float), stream);
    prep_kernel<<<(BB * LL) / 4, 256, 0, stream>>>(in, Af, Rf);
    score_kernel<<<dim3(BB / TI, BB), 256, 0, stream>>>(Af, Rf, ET);
    rowreduce_kernel<<<BB, 256, 0, stream>>>(ET, label, out);
}

// Round 5
// 126.663 us; speedup vs baseline: 2.4947x; 1.0175x over previous
//
#include <hip/hip_runtime.h>
#include <math.h>

#define BB 512
#define LL 128
#define DD 256
#define NREST 127            // L-1
#define EPSN 1e-12f

#define TI 128               // i-tile and k-tile per block

typedef float f32x4 __attribute__((ext_vector_type(4)));
typedef long  long2v __attribute__((ext_vector_type(2)));

// async global->LDS, 16B per lane; LDS base wave-uniform (HW adds lane*16)
#define GLD16(gp, lp) __builtin_amdgcn_global_load_lds( \
    (const __attribute__((address_space(1))) void*)(gp), \
    (__attribute__((address_space(3))) void*)(lp), 16, 0, 0)

// ---- Kernel 1: norm + normalize + cvt fp8(e4m3), column-permuted, split Af/Rf ----
// Row layout (256 B): within each 64-byte block, 8-byte groups stored in order
// 0,4,1,5,2,6,3,7 (orig group g -> pos g<4 ? 2g : 2(g-4)+1). A 16-byte LDS
// fragment read at offset quad*16 then yields [ks0 frag | ks1 frag] for that quad.
// Rf[b][r] holds row l=r+1; Rf[b][127] zeroed so score needs no masking while staging.
__global__ __launch_bounds__(256) void prep_kernel(const float* __restrict__ in,
                                                   unsigned char* __restrict__ Af,
                                                   unsigned char* __restrict__ Rf) {
    int wid  = threadIdx.x >> 6;
    int lane = threadIdx.x & 63;
    int row  = blockIdx.x * 4 + wid;            // 0..65535
    int b    = row >> 7;
    int l    = row & 127;
    const float4 v = ((const float4*)(in + (size_t)row * DD))[lane];
    float ss = v.x*v.x + v.y*v.y + v.z*v.z + v.w*v.w;
    #pragma unroll
    for (int off = 32; off; off >>= 1) ss += __shfl_xor(ss, off);
    float sc = 1.0f / fmaxf(sqrtf(ss), EPSN);

    int p = __builtin_amdgcn_cvt_pk_fp8_f32(v.x * sc, v.y * sc, 0, false);
    p     = __builtin_amdgcn_cvt_pk_fp8_f32(v.z * sc, v.w * sc, p, true);

    // permuted byte offset for this lane's 4 elements (orig elems 4*lane..4*lane+3)
    int g_all = lane >> 1;                 // 8-elem group 0..31
    int blk   = g_all >> 3;                // 64-elem block 0..3
    int g     = g_all & 7;
    int ng    = (g < 4) ? (2 * g) : (2 * (g - 4) + 1);
    int off   = blk * 64 + ng * 8 + (lane & 1) * 4;

    if (l == 0) {
        *(unsigned int*)(Af + (size_t)b * DD + off) = (unsigned int)p;
        *(unsigned int*)(Rf + ((size_t)b * LL + 127) * DD + off) = 0u;  // pad row
    } else {
        *(unsigned int*)(Rf + ((size_t)b * LL + (l - 1)) * DD + off) = (unsigned int)p;
    }
}

// ------- Kernel 2: fp8 MFMA scores + exp + k-sum -> E^T[j][i] -------
// Block: 128 anchors x 128 rest rows (127 valid) of batch j, FULL K = 256 staged
// upfront as 4 planes of [128 rows x 64 B] per operand (64 KB LDS total), ONE
// barrier, then 128 MFMA/wave with no intermediate vmcnt drains.
__global__ __launch_bounds__(256) void score_kernel(const unsigned char* __restrict__ Af,
                                                    const unsigned char* __restrict__ Rf,
                                                    float* __restrict__ ET) {
    __shared__ unsigned char sA[4 * TI * 64];   // 32 KB: plane p at p*8192
    __shared__ unsigned char sR[4 * TI * 64];   // 32 KB
    __shared__ float         sP[TI * 2];

    const int tid  = threadIdx.x;
    const int i0   = blockIdx.x * TI;
    const int j    = blockIdx.y;

    const int lane = tid & 63;
    const int w    = tid >> 6;
    const int wm   = w & 1;            // wave row (i)
    const int wn   = w >> 1;           // wave col (k_rest)
    const int rowf = lane & 15;
    const int quad = lane >> 4;
    const int lrow = lane >> 2;        // staging: row within 16-row group
    const int gct  = lane & 3;         // staging: 16B granule within 64B row

    f32x4 acc[4][4];
    #pragma unroll
    for (int a = 0; a < 4; ++a)
        #pragma unroll
        for (int b = 0; b < 4; ++b) acc[a][b] = (f32x4){0.f, 0.f, 0.f, 0.f};

    const unsigned char* aBase = Af + (size_t)i0 * DD;
    const unsigned char* rBase = Rf + (size_t)j * LL * DD;

    // ---- stage ALL of K: 64 x 1KB async loads, then one barrier ----
    #pragma unroll
    for (int p = 0; p < 4; ++p) {
        #pragma unroll
        for (int t = 0; t < 2; ++t) {
            int grp = w * 2 + t;               // 0..7, 16 rows each
            int r   = grp * 16 + lrow;
            GLD16(aBase + (size_t)r * DD + p * 64 + gct * 16, &sA[p * 8192 + grp * 1024]);
            GLD16(rBase + (size_t)r * DD + p * 64 + gct * 16, &sR[p * 8192 + grp * 1024]);
        }
    }
    __syncthreads();

    // ---- MFMA over all 4 planes (K=64 each), no barriers inside ----
    #pragma unroll
    for (int p = 0; p < 4; ++p) {
        long a0[4], a1[4], b0[4], b1[4];
        #pragma unroll
        for (int mt = 0; mt < 4; ++mt) {
            long2v lv = *(const long2v*)(&sA[p * 8192 + (wm * 64 + mt * 16 + rowf) * 64 + quad * 16]);
            a0[mt] = lv.x; a1[mt] = lv.y;
        }
        #pragma unroll
        for (int nt = 0; nt < 4; ++nt) {
            long2v lv = *(const long2v*)(&sR[p * 8192 + (wn * 64 + nt * 16 + rowf) * 64 + quad * 16]);
            b0[nt] = lv.x; b1[nt] = lv.y;
        }
        #pragma unroll
        for (int mt = 0; mt < 4; ++mt)
            #pragma unroll
            for (int nt = 0; nt < 4; ++nt)
                acc[mt][nt] = __builtin_amdgcn_mfma_f32_16x16x32_fp8_fp8(a0[mt], b0[nt], acc[mt][nt], 0, 0, 0);
        #pragma unroll
        for (int mt = 0; mt < 4; ++mt)
            #pragma unroll
            for (int nt = 0; nt < 4; ++nt)
                acc[mt][nt] = __builtin_amdgcn_mfma_f32_16x16x32_fp8_fp8(a1[mt], b1[nt], acc[mt][nt], 0, 0, 0);
    }

    // ---- epilogue: exp + sum over this wave's 64 k values ----
    // C/D layout: col(n) = lane&15, row(m) = quad*4 + reg (verified R2-R4)
    #pragma unroll
    for (int mt = 0; mt < 4; ++mt) {
        float s[4];
        #pragma unroll
        for (int r = 0; r < 4; ++r) s[r] = 0.f;
        #pragma unroll
        for (int nt = 0; nt < 4; ++nt) {
            int n = wn * 64 + nt * 16 + rowf;   // global k_rest index
            bool valid = (n < NREST);
            #pragma unroll
            for (int r = 0; r < 4; ++r)
                if (valid) s[r] += __expf(acc[mt][nt][r]);
        }
        #pragma unroll
        for (int r = 0; r < 4; ++r) {
            #pragma unroll
            for (int off = 1; off < 16; off <<= 1) s[r] += __shfl_xor(s[r], off);
        }
        if (rowf == 0) {
            #pragma unroll
            for (int r = 0; r < 4; ++r)
                sP[(wm * 64 + mt * 16 + quad * 4 + r) * 2 + wn] = s[r];
        }
    }
    __syncthreads();
    if (tid < TI) {
        float e = sP[tid * 2] + sP[tid * 2 + 1];
        ET[(size_t)j * BB + i0 + tid] = e;      // coalesced over i
    }
}

// ---- Kernel 3: per-i tot/pos, log term, atomic mean into out ----
__global__ __launch_bounds__(256) void rowreduce_kernel(const float* __restrict__ ET,
                                                        const int* __restrict__ label,
                                                        float* __restrict__ out) {
    int i  = blockIdx.x;
    int li = label[i];
    float tot = 0.f, pos = 0.f;
    for (int jj = threadIdx.x; jj < BB; jj += 256) {
        float e = ET[(size_t)jj * BB + i];
        tot += e;
        if (label[jj] == li) pos += e;
    }
    #pragma unroll
    for (int off = 32; off; off >>= 1) {
        tot += __shfl_xor(tot, off);
        pos += __shfl_xor(pos, off);
    }
    __shared__ float st[4], sp[4];
    int wid = threadIdx.x >> 6;
    if ((threadIdx.x & 63) == 0) { st[wid] = tot; sp[wid] = pos; }
    __syncthreads();
    if (threadIdx.x == 0) {
        float t = st[0] + st[1] + st[2] + st[3];
        float p = sp[0] + sp[1] + sp[2] + sp[3];
        atomicAdd(out, (logf(t) - logf(p)) * (1.0f / BB));
    }
}

extern "C" void kernel_launch(void* const* d_in, const int* in_sizes, int n_in,
                              void* d_out, int out_size, void* d_ws, size_t ws_size,
                              hipStream_t stream) {
    const float* in    = (const float*)d_in[0];
    const int*   label = (const int*)d_in[1];
    float*       out   = (float*)d_out;

    unsigned char* Af = (unsigned char*)d_ws;             // 512*256 B (128 KB)
    unsigned char* Rf = Af + (size_t)BB * DD;             // 512*128*256 B (16 MB)
    float*         ET = (float*)(Rf + (size_t)BB * LL * DD); // 512*512 f32 (1 MB)

    hipMemsetAsync(out, 0, sizeof(float), stream);
    prep_kernel<<<(BB * LL) / 4, 256, 0, stream>>>(in, Af, Rf);
    score_kernel<<<dim3(BB / TI, BB), 256, 0, stream>>>(Af, Rf, ET);
    rowreduce_kernel<<<BB, 256, 0, stream>>>(ET, label, out);
}

// Round 6
// 121.093 us; speedup vs baseline: 2.6095x; 1.0460x over previous
//
#include <hip/hip_runtime.h>
#include <math.h>

#define BB 512
#define LL 128
#define DD 256
#define NREST 127            // L-1
#define EPSN 1e-12f

#define TI 128               // i-tile and k-tile per block

typedef float f32x4 __attribute__((ext_vector_type(4)));
typedef long  long2v __attribute__((ext_vector_type(2)));

// async global->LDS, 16B per lane; LDS base wave-uniform (HW adds lane*16)
#define GLD16(gp, lp) __builtin_amdgcn_global_load_lds( \
    (const __attribute__((address_space(1))) void*)(gp), \
    (__attribute__((address_space(3))) void*)(lp), 16, 0, 0)

// ---- Kernel 1: norm + normalize + cvt fp8(e4m3), column-permuted, split Af/Rf ----
// Row layout (256 B): within each 64-byte block, 8-byte groups stored in order
// 0,4,1,5,2,6,3,7 (orig group g -> pos g<4 ? 2g : 2(g-4)+1). A 16-byte LDS
// fragment read at offset quad*16 then yields [ks0 frag | ks1 frag] for that quad.
// Rf[b][r] holds row l=r+1; Rf[b][127] zeroed so score needs no masking while staging.
// Block 0 additionally zeroes tot/pos (stream-ordered before score's atomics).
__global__ __launch_bounds__(256) void prep_kernel(const float* __restrict__ in,
                                                   unsigned char* __restrict__ Af,
                                                   unsigned char* __restrict__ Rf,
                                                   float* __restrict__ totpos) {
    if (blockIdx.x == 0) {
        ((f32x4*)totpos)[threadIdx.x] = (f32x4){0.f, 0.f, 0.f, 0.f};  // 1024 floats
    }
    int wid  = threadIdx.x >> 6;
    int lane = threadIdx.x & 63;
    int row  = blockIdx.x * 4 + wid;            // 0..65535
    int b    = row >> 7;
    int l    = row & 127;
    const float4 v = ((const float4*)(in + (size_t)row * DD))[lane];
    float ss = v.x*v.x + v.y*v.y + v.z*v.z + v.w*v.w;
    #pragma unroll
    for (int off = 32; off; off >>= 1) ss += __shfl_xor(ss, off);
    float sc = 1.0f / fmaxf(sqrtf(ss), EPSN);

    int p = __builtin_amdgcn_cvt_pk_fp8_f32(v.x * sc, v.y * sc, 0, false);
    p     = __builtin_amdgcn_cvt_pk_fp8_f32(v.z * sc, v.w * sc, p, true);

    // permuted byte offset for this lane's 4 elements (orig elems 4*lane..4*lane+3)
    int g_all = lane >> 1;                 // 8-elem group 0..31
    int blk   = g_all >> 3;                // 64-elem block 0..3
    int g     = g_all & 7;
    int ng    = (g < 4) ? (2 * g) : (2 * (g - 4) + 1);
    int off   = blk * 64 + ng * 8 + (lane & 1) * 4;

    if (l == 0) {
        *(unsigned int*)(Af + (size_t)b * DD + off) = (unsigned int)p;
        *(unsigned int*)(Rf + ((size_t)b * LL + 127) * DD + off) = 0u;  // pad row
    } else {
        *(unsigned int*)(Rf + ((size_t)b * LL + (l - 1)) * DD + off) = (unsigned int)p;
    }
}

// ------- Kernel 2: fp8 MFMA scores + exp + k-sum + fused atomic row-reduce -------
// Block: 128 anchors x 128 rest rows (127 valid) of batch j, FULL K = 256 staged
// upfront (64 KB LDS), ONE barrier, 128 MFMA/wave, then exp + per-i sums and
// device atomicAdd into tot[i] / pos[i] (label-gated).
__global__ __launch_bounds__(256) void score_kernel(const unsigned char* __restrict__ Af,
                                                    const unsigned char* __restrict__ Rf,
                                                    const int* __restrict__ label,
                                                    float* __restrict__ tot,
                                                    float* __restrict__ pos) {
    __shared__ unsigned char sA[4 * TI * 64];   // 32 KB: plane p at p*8192
    __shared__ unsigned char sR[4 * TI * 64];   // 32 KB
    __shared__ float         sP[TI * 2];

    const int tid  = threadIdx.x;
    const int i0   = blockIdx.x * TI;
    const int j    = blockIdx.y;

    const int lane = tid & 63;
    const int w    = tid >> 6;
    const int wm   = w & 1;            // wave row (i)
    const int wn   = w >> 1;           // wave col (k_rest)
    const int rowf = lane & 15;
    const int quad = lane >> 4;
    const int lrow = lane >> 2;        // staging: row within 16-row group
    const int gct  = lane & 3;         // staging: 16B granule within 64B row

    f32x4 acc[4][4];
    #pragma unroll
    for (int a = 0; a < 4; ++a)
        #pragma unroll
        for (int b = 0; b < 4; ++b) acc[a][b] = (f32x4){0.f, 0.f, 0.f, 0.f};

    const unsigned char* aBase = Af + (size_t)i0 * DD;
    const unsigned char* rBase = Rf + (size_t)j * LL * DD;

    // ---- stage ALL of K: 64 x 1KB async loads, then one barrier ----
    #pragma unroll
    for (int p = 0; p < 4; ++p) {
        #pragma unroll
        for (int t = 0; t < 2; ++t) {
            int grp = w * 2 + t;               // 0..7, 16 rows each
            int r   = grp * 16 + lrow;
            GLD16(aBase + (size_t)r * DD + p * 64 + gct * 16, &sA[p * 8192 + grp * 1024]);
            GLD16(rBase + (size_t)r * DD + p * 64 + gct * 16, &sR[p * 8192 + grp * 1024]);
        }
    }
    __syncthreads();

    // ---- MFMA over all 4 planes (K=64 each), no barriers inside ----
    #pragma unroll
    for (int p = 0; p < 4; ++p) {
        long a0[4], a1[4], b0[4], b1[4];
        #pragma unroll
        for (int mt = 0; mt < 4; ++mt) {
            long2v lv = *(const long2v*)(&sA[p * 8192 + (wm * 64 + mt * 16 + rowf) * 64 + quad * 16]);
            a0[mt] = lv.x; a1[mt] = lv.y;
        }
        #pragma unroll
        for (int nt = 0; nt < 4; ++nt) {
            long2v lv = *(const long2v*)(&sR[p * 8192 + (wn * 64 + nt * 16 + rowf) * 64 + quad * 16]);
            b0[nt] = lv.x; b1[nt] = lv.y;
        }
        #pragma unroll
        for (int mt = 0; mt < 4; ++mt)
            #pragma unroll
            for (int nt = 0; nt < 4; ++nt)
                acc[mt][nt] = __builtin_amdgcn_mfma_f32_16x16x32_fp8_fp8(a0[mt], b0[nt], acc[mt][nt], 0, 0, 0);
        #pragma unroll
        for (int mt = 0; mt < 4; ++mt)
            #pragma unroll
            for (int nt = 0; nt < 4; ++nt)
                acc[mt][nt] = __builtin_amdgcn_mfma_f32_16x16x32_fp8_fp8(a1[mt], b1[nt], acc[mt][nt], 0, 0, 0);
    }

    // ---- epilogue: exp + sum over this wave's 64 k values ----
    // C/D layout: col(n) = lane&15, row(m) = quad*4 + reg (verified R2-R5)
    #pragma unroll
    for (int mt = 0; mt < 4; ++mt) {
        float s[4];
        #pragma unroll
        for (int r = 0; r < 4; ++r) s[r] = 0.f;
        #pragma unroll
        for (int nt = 0; nt < 4; ++nt) {
            int n = wn * 64 + nt * 16 + rowf;   // global k_rest index
            bool valid = (n < NREST);
            #pragma unroll
            for (int r = 0; r < 4; ++r)
                if (valid) s[r] += __expf(acc[mt][nt][r]);
        }
        #pragma unroll
        for (int r = 0; r < 4; ++r) {
            #pragma unroll
            for (int off = 1; off < 16; off <<= 1) s[r] += __shfl_xor(s[r], off);
        }
        if (rowf == 0) {
            #pragma unroll
            for (int r = 0; r < 4; ++r)
                sP[(wm * 64 + mt * 16 + quad * 4 + r) * 2 + wn] = s[r];
        }
    }
    __syncthreads();
    if (tid < TI) {
        int i = i0 + tid;
        float e = sP[tid * 2] + sP[tid * 2 + 1];
        atomicAdd(&tot[i], e);
        if (label[j] == label[i]) atomicAdd(&pos[i], e);
    }
}

// ---- Kernel 3: loss = mean_i( log tot[i] - log pos[i] ) ----
__global__ __launch_bounds__(256) void final_kernel(const float* __restrict__ tot,
                                                    const float* __restrict__ pos,
                                                    float* __restrict__ out) {
    int t0 = threadIdx.x, t1 = threadIdx.x + 256;
    float s = (logf(tot[t0]) - logf(pos[t0])) + (logf(tot[t1]) - logf(pos[t1]));
    #pragma unroll
    for (int off = 32; off; off >>= 1) s += __shfl_xor(s, off);
    __shared__ float sw[4];
    int wid = threadIdx.x >> 6;
    if ((threadIdx.x & 63) == 0) sw[wid] = s;
    __syncthreads();
    if (threadIdx.x == 0) out[0] = (sw[0] + sw[1] + sw[2] + sw[3]) * (1.0f / BB);
}

extern "C" void kernel_launch(void* const* d_in, const int* in_sizes, int n_in,
                              void* d_out, int out_size, void* d_ws, size_t ws_size,
                              hipStream_t stream) {
    const float* in    = (const float*)d_in[0];
    const int*   label = (const int*)d_in[1];
    float*       out   = (float*)d_out;

    unsigned char* Af  = (unsigned char*)d_ws;               // 512*256 B (128 KB)
    unsigned char* Rf  = Af + (size_t)BB * DD;               // 512*128*256 B (16 MB)
    float*         tot = (float*)(Rf + (size_t)BB * LL * DD); // 512 f32
    float*         pos = tot + BB;                            // 512 f32

    prep_kernel<<<(BB * LL) / 4, 256, 0, stream>>>(in, Af, Rf, tot);
    score_kernel<<<dim3(BB / TI, BB), 256, 0, stream>>>(Af, Rf, label, tot, pos);
    final_kernel<<<1, 256, 0, stream>>>(tot, pos, out);
}